// Round 13
// baseline (13472.443 us; speedup 1.0000x reference)
//
#include <hip/hip_runtime.h>

// DA-RNN decoder: B=512, T=128, E=256, D=256, OUT=1.
// R13: R6 skeleton (one 1024-thread block/CU, NB=2, ep in LDS, weights
// streamed global->VGPR with immediate consumption -- every buffering scheme
// R7-R12 lost to this). Deltas vs R6:
//  1. gates GEMM moved INTO the scores phase, 4 octets per score-group,
//     straight-line named loads (dependency-legal: gates need only h(t)).
//  2. pre-exponentiated ep: pe = exp(2*ep) stored f16 at encproj; scores
//     use rcp(pe*pq+1) -- kills 64 per-thread per-step exp ops.
//  3. q-GEMM 4-way K-split (aW1 read once); merged C+D. 3 barriers/step.

#define BB 512
#define TT 128
#define EE 256
#define DD 256
#define NB 2
#define NTHR 1024

typedef _Float16 h2 __attribute__((ext_vector_type(2)));
typedef _Float16 h8 __attribute__((ext_vector_type(8)));

#if defined(__has_builtin)
#if __has_builtin(__builtin_amdgcn_fdot2)
#define HAS_FDOT2 1
#endif
#endif

#ifdef HAS_FDOT2
#define FDOT2(a, b, c) __builtin_amdgcn_fdot2(__builtin_bit_cast(h2, (a)), __builtin_bit_cast(h2, (b)), (c), false)
#else
static __device__ __forceinline__ float FDOT2(unsigned int a, unsigned int b, float c) {
    h2 x = __builtin_bit_cast(h2, a), y = __builtin_bit_cast(h2, b);
    return c + (float)x[0] * (float)y[0] + (float)x[1] * (float)y[1];
}
#endif

static __device__ __forceinline__ float dot8u4(uint4 w, uint4 h, float acc) {
    acc = FDOT2(w.x, h.x, acc);
    acc = FDOT2(w.y, h.y, acc);
    acc = FDOT2(w.z, h.z, acc);
    acc = FDOT2(w.w, h.w, acc);
    return acc;
}
static __device__ __forceinline__ unsigned int pkh(float a, float b) {
    union { _Float16 h; unsigned short s; } ua, ub;
    ua.h = (_Float16)a; ub.h = (_Float16)b;
    return (unsigned int)ua.s | ((unsigned int)ub.s << 16);
}
__device__ __forceinline__ float ftanh(float x) {
    return 1.f - 2.f * __builtin_amdgcn_rcpf(__expf(2.f * x) + 1.f);
}
__device__ __forceinline__ float fsig(float x) {
    return __builtin_amdgcn_rcpf(1.f + __expf(-x));
}

// Pack weights to f16 in the exact load order of k_main.
// aW1h[(g*256+f)*8+j] = aW1[g*8+j][f]      (g<64, k=g*8+j < 512)
// WhhH[(i*1024+jj)*8+m] = Whh[jj][i*8+m]   (i<32)
__global__ __launch_bounds__(256) void k_pack(const float* __restrict__ aW1,
                                              const float* __restrict__ Whh,
                                              const float* __restrict__ bih,
                                              const float* __restrict__ bhh,
                                              _Float16* __restrict__ aW1h,
                                              _Float16* __restrict__ WhhH,
                                              float* __restrict__ bias) {
    int bid = blockIdx.x, tid = threadIdx.x;
    if (bid < 512) {
        int o = bid * 256 + tid;                 // < 131072
        int g = o >> 11, f = (o >> 3) & 255, j = o & 7;
        aW1h[o] = (_Float16)aW1[(g * 8 + j) * EE + f];
    } else if (bid < 1536) {
        int o = (bid - 512) * 256 + tid;         // < 262144
        int i = o >> 13, jj = (o >> 3) & 1023, m = o & 7;
        WhhH[o] = (_Float16)Whh[jj * DD + i * 8 + m];
    } else {
        int j = (bid - 1536) * 256 + tid;        // < 1024
        bias[j] = bih[j] + bhh[j];
    }
}

// pe[n][f] = f16( exp(2 * sum_e ie[n][e]*aW1[512+e][f]) )   (pre-exponentiated)
// epilogue: iefc[n] = dot(ie[n], fcW[0:256]); ieff[n] = dot(ie[n], ffW[256:512])
__global__ __launch_bounds__(256) void k_encproj(const float* __restrict__ ie,
                                                 const float* __restrict__ aW1,
                                                 const float* __restrict__ fcW,
                                                 const float* __restrict__ ffW,
                                                 _Float16* __restrict__ ep,
                                                 float* __restrict__ iefc,
                                                 float* __restrict__ ieff) {
    __shared__ float a[32][EE];
    int row0 = blockIdx.x * 32;
    int tid = threadIdx.x;
    for (int r = 0; r < 32; ++r)
        a[r][tid] = ie[(size_t)(row0 + r) * EE + tid];
    __syncthreads();
    float acc[32];
    #pragma unroll
    for (int r = 0; r < 32; ++r) acc[r] = 0.f;
    const float* wenc = aW1 + 512 * EE;
    for (int e = 0; e < EE; e += 4) {
        float w0 = wenc[(e + 0) * EE + tid];
        float w1 = wenc[(e + 1) * EE + tid];
        float w2 = wenc[(e + 2) * EE + tid];
        float w3 = wenc[(e + 3) * EE + tid];
        #pragma unroll
        for (int r = 0; r < 32; ++r) {
            float4 av = *(const float4*)&a[r][e];
            acc[r] += av.x * w0 + av.y * w1 + av.z * w2 + av.w * w3;
        }
    }
    for (int r = 0; r < 32; ++r)
        ep[(size_t)(row0 + r) * EE + tid] =
            (_Float16)fminf(__expf(2.f * acc[r]), 60000.f);

    int wave = tid >> 6, lane = tid & 63;
    float4 f1 = *(const float4*)&fcW[lane * 4];
    float4 f2 = *(const float4*)&ffW[EE + lane * 4];
    #pragma unroll
    for (int rr = 0; rr < 8; ++rr) {
        int r = wave * 8 + rr;
        float4 v = *(const float4*)&a[r][lane * 4];
        float p1 = v.x * f1.x + v.y * f1.y + v.z * f1.z + v.w * f1.w;
        float p2 = v.x * f2.x + v.y * f2.y + v.z * f2.z + v.w * f2.w;
        #pragma unroll
        for (int off = 1; off <= 32; off <<= 1) {
            p1 += __shfl_xor(p1, off);
            p2 += __shfl_xor(p2, off);
        }
        if (lane == 0) {
            iefc[row0 + r] = p1;
            ieff[row0 + r] = p2;
        }
    }
}

__global__ __launch_bounds__(NTHR) void k_main(
    const _Float16* __restrict__ ep, const float* __restrict__ yh,
    const _Float16* __restrict__ aW1h, const _Float16* __restrict__ WhhH,
    const float* __restrict__ bias_, const float* __restrict__ ab1,
    const float* __restrict__ aW2, const float* __restrict__ Wih,
    const float* __restrict__ fcW, const float* __restrict__ fcb,
    const float* __restrict__ ffW, const float* __restrict__ ffb,
    const float* __restrict__ iefc, const float* __restrict__ ieff,
    float* __restrict__ out) {
    __shared__ _Float16 s_ep[NB * TT * EE];      // 128 KB: pe slice (exp'd)
    __shared__ unsigned int s_hc16[NB][2][128];  // [b][0=h,1=c], f16 pairs
    __shared__ float s_qp[4][NB][EE];            // [kq][b][32*(f&7)+(f>>3)]
    __shared__ float s_sc[NB * TT];
    __shared__ float s_g[NB][4 * DD];            // h.Whh + bias (yt added later)
    __shared__ float s_wih[4 * DD];
    __shared__ float s_iefc[NB][TT];
    __shared__ float s_ieff[NB][TT];
    __shared__ float s_yh[NB][TT];

    const int tid = threadIdx.x;
    const int wave = tid >> 6, lane = tid & 63;
    const int b0 = blockIdx.x * NB;

    // one-time staging
    {
        const uint4* src = (const uint4*)(ep + (size_t)b0 * TT * EE);
        uint4* dst = (uint4*)s_ep;
        #pragma unroll
        for (int i = 0; i < (NB * TT * EE) / 8 / NTHR; ++i)
            dst[tid + i * NTHR] = src[tid + i * NTHR];
    }
    for (int i = tid; i < 4 * DD; i += NTHR) s_wih[i] = Wih[i];
    for (int i = tid; i < NB * TT; i += NTHR) {
        int b = i >> 7, t = i & 127;
        s_iefc[b][t] = iefc[(b0 + b) * TT + t];
        s_ieff[b][t] = ieff[(b0 + b) * TT + t];
        s_yh[b][t]   = yh[(size_t)(b0 + b) * TT + t];
    }
    for (int i = tid; i < NB * 2 * 128; i += NTHR) (&s_hc16[0][0][0])[i] = 0u;

    // ----- q mapping: thread = (kq, qf); kq = K-quarter, both batch rows -----
    const int qf = tid & 255, kq = tid >> 8;     // kq in [0,4)
    const float qinit = (kq == 0) ? ab1[qf] : 0.f;
    const uint4* qW = (const uint4*)aW1h + ((size_t)(kq * 16) * 256 + qf);
    const int qperm = 32 * (qf & 7) + (qf >> 3);
    const int qhc  = kq >> 1;                    // 0 = h-half, 1 = c-half
    const int qoff = (kq & 1) * 64;              // uint index base within row

    // ----- gates mapping: thread = gate row tid (both batch rows) -----
    const uint4* wP = (const uint4*)WhhH + tid;
    const float biasv = bias_[tid];

    // ----- scores mapping -----
    const int l5 = lane & 31;
    const int rsub = wave * 2 + (lane >> 5);     // [0,32)
    const int e0 = l5 * 8;
    float tw2[8]; float sw2 = 0.f;
    #pragma unroll
    for (int j = 0; j < 8; ++j) { float w = aW2[e0 + j]; tw2[j] = 2.f * w; sw2 += w; }

    // ----- softmax/update mapping: wave -> batch row -----
    const int bsm = (wave >> 2) & 1;             // waves 0-3:b0, 4-7:b1 (8-15 redundant)
    const float fcw256 = fcW[256], fcb0 = fcb[0], ffb0 = ffb[0];
    float c_reg = 0.f;                           // fp32 cell state (tid<512)
    float ofs_reg = 0.f;

    __syncthreads();

    for (int t = 0; t < TT; ++t) {
        // ---------- A: q K-quarter only (aW1 streamed once across block) ----------
        float qa0 = qinit, qa1 = qinit;
        #pragma unroll
        for (int i = 0; i < 16; ++i) {
            uint4 qwv = qW[(size_t)i * 256];
            uint4 hq0 = *(const uint4*)&s_hc16[0][qhc][qoff + i * 4];
            uint4 hq1 = *(const uint4*)&s_hc16[1][qhc][qoff + i * 4];
            qa0 = dot8u4(qwv, hq0, qa0);
            qa1 = dot8u4(qwv, hq1, qa1);
        }
        s_qp[kq][0][qperm] = qa0;
        s_qp[kq][1][qperm] = qa1;
        __syncthreads();

        // ---------- B: scores (rcp-only, pe pre-exp'd) + gates interleaved ----------
        float g0 = biasv, g1 = biasv;
        #pragma unroll
        for (int b = 0; b < NB; ++b) {
            float pq[8];
            #pragma unroll
            for (int j = 0; j < 8; ++j) {
                int ix = l5 + 32 * j;
                pq[j] = __expf(2.f * (s_qp[0][b][ix] + s_qp[1][b][ix]
                                    + s_qp[2][b][ix] + s_qp[3][b][ix]));
            }
            const _Float16* eph = s_ep + b * TT * EE + e0;
            #pragma unroll
            for (int sw = 0; sw < 4; ++sw) {
                // score group: 8 elements, rcp only
                int tt2 = sw * 32 + rsub;
                h8 xv = *(const h8*)(eph + tt2 * EE);
                float s = sw2;
                #pragma unroll
                for (int j = 0; j < 8; ++j) {
                    float pe = (float)xv[j];
                    float den = __fmaf_rn(pe, pq[j], 1.f);
                    s = __fmaf_rn(-tw2[j], __builtin_amdgcn_rcpf(den), s);
                }
                #pragma unroll
                for (int off = 1; off <= 16; off <<= 1) s += __shfl_xor(s, off);
                if (l5 == 0) s_sc[b * TT + tt2] = s;
                // 4 gate octets, straight-line named loads (no arrays)
                const int oc = (b * 4 + sw) * 4;
                {
                    uint4 gw = wP[(size_t)(oc + 0) * 1024];
                    uint4 h0 = *(const uint4*)&s_hc16[0][0][(oc + 0) * 4];
                    uint4 h1 = *(const uint4*)&s_hc16[1][0][(oc + 0) * 4];
                    g0 = dot8u4(gw, h0, g0); g1 = dot8u4(gw, h1, g1);
                }
                {
                    uint4 gw = wP[(size_t)(oc + 1) * 1024];
                    uint4 h0 = *(const uint4*)&s_hc16[0][0][(oc + 1) * 4];
                    uint4 h1 = *(const uint4*)&s_hc16[1][0][(oc + 1) * 4];
                    g0 = dot8u4(gw, h0, g0); g1 = dot8u4(gw, h1, g1);
                }
                {
                    uint4 gw = wP[(size_t)(oc + 2) * 1024];
                    uint4 h0 = *(const uint4*)&s_hc16[0][0][(oc + 2) * 4];
                    uint4 h1 = *(const uint4*)&s_hc16[1][0][(oc + 2) * 4];
                    g0 = dot8u4(gw, h0, g0); g1 = dot8u4(gw, h1, g1);
                }
                {
                    uint4 gw = wP[(size_t)(oc + 3) * 1024];
                    uint4 h0 = *(const uint4*)&s_hc16[0][0][(oc + 3) * 4];
                    uint4 h1 = *(const uint4*)&s_hc16[1][0][(oc + 3) * 4];
                    g0 = dot8u4(gw, h0, g0); g1 = dot8u4(gw, h1, g1);
                }
            }
        }
        s_g[0][tid] = g0;
        s_g[1][tid] = g1;
        __syncthreads();

        // ---------- C+D: all-wave shfl softmax + y_tilde + LSTM update ----------
        {
            float v0 = s_sc[bsm * TT + lane], v1 = s_sc[bsm * TT + 64 + lane];
            float m = fmaxf(v0, v1);
            #pragma unroll
            for (int off = 1; off <= 32; off <<= 1) m = fmaxf(m, __shfl_xor(m, off));
            float x0 = __expf(v0 - m), x1 = __expf(v1 - m);
            float ss = x0 + x1;
            #pragma unroll
            for (int off = 1; off <= 32; off <<= 1) ss += __shfl_xor(ss, off);
            float inv = __builtin_amdgcn_rcpf(ss);
            float a0 = x0 * inv, a1 = x1 * inv;
            float p = a0 * s_iefc[bsm][lane] + a1 * s_iefc[bsm][64 + lane];
            #pragma unroll
            for (int off = 1; off <= 32; off <<= 1) p += __shfl_xor(p, off);
            float yt = p + s_yh[bsm][t] * fcw256 + fcb0;
            if (t == TT - 1) {
                float pf = a0 * s_ieff[bsm][lane] + a1 * s_ieff[bsm][64 + lane];
                #pragma unroll
                for (int off = 1; off <= 32; off <<= 1) pf += __shfl_xor(pf, off);
                ofs_reg = pf;
            }
            if (tid < NB * DD) {
                int d = tid & 255;               // batch row = bsm (waves 0-7)
                float gi = s_g[bsm][d]          + yt * s_wih[d];
                float gf = s_g[bsm][DD + d]     + yt * s_wih[DD + d];
                float gg = s_g[bsm][2 * DD + d] + yt * s_wih[2 * DD + d];
                float go = s_g[bsm][3 * DD + d] + yt * s_wih[3 * DD + d];
                float c2 = fsig(gf) * c_reg + fsig(gi) * ftanh(gg);
                c_reg = c2;
                float hn = fsig(go) * ftanh(c2);
                float hO = __shfl_xor(hn, 1);
                float cO = __shfl_xor(c2, 1);
                if (!(d & 1)) {
                    s_hc16[bsm][0][d >> 1] = pkh(hn, hO);
                    s_hc16[bsm][1][d >> 1] = pkh(c2, cO);
                }
            }
        }
        __syncthreads();
    }

    // ---------- final: out[b] = h.ffW[:256] + (attn_last . ieff) + ffb ----------
    if (wave == 0 || wave == 4) {
        int b = wave >> 2;
        unsigned int p0 = s_hc16[b][0][lane * 2];
        unsigned int p1 = s_hc16[b][0][lane * 2 + 1];
        h2 ha = __builtin_bit_cast(h2, p0), hb = __builtin_bit_cast(h2, p1);
        float4 w = *(const float4*)&ffW[lane * 4];
        float p = (float)ha[0] * w.x + (float)ha[1] * w.y
                + (float)hb[0] * w.z + (float)hb[1] * w.w;
        #pragma unroll
        for (int off = 1; off <= 32; off <<= 1) p += __shfl_xor(p, off);
        if (lane == 0) out[b0 + b] = p + ofs_reg + ffb0;
    }
}

extern "C" void kernel_launch(void* const* d_in, const int* in_sizes, int n_in,
                              void* d_out, int out_size, void* d_ws, size_t ws_size,
                              hipStream_t stream) {
    const float* ie  = (const float*)d_in[0];   // [B,T,E]
    const float* yh  = (const float*)d_in[1];   // [B,T,1]
    const float* aW1 = (const float*)d_in[2];   // [768,256]
    const float* ab1 = (const float*)d_in[3];   // [256]
    const float* aW2 = (const float*)d_in[4];   // [256,1]
    // d_in[5] = ab2: additive constant inside softmax -> invariant, unused
    const float* Wih = (const float*)d_in[6];   // [1024,1]
    const float* Whh = (const float*)d_in[7];   // [1024,256]
    const float* bih = (const float*)d_in[8];   // [1024]
    const float* bhh = (const float*)d_in[9];   // [1024]
    const float* fcW = (const float*)d_in[10];  // [1,257]
    const float* fcb = (const float*)d_in[11];  // [1]
    const float* ffW = (const float*)d_in[12];  // [1,512]
    const float* ffb = (const float*)d_in[13];  // [1]
    float* out = (float*)d_out;

    // workspace layout
    _Float16* ep   = (_Float16*)d_ws;                        // 16,777,216 f16 = 32 MiB
    _Float16* aW1h = ep + (size_t)BB * TT * EE;              // 131072 f16
    _Float16* WhhH = aW1h + 512 * EE;                        // 262144 f16
    float* bias = (float*)(WhhH + 262144);                   // 1024 f32
    float* iefc = bias + 1024;                               // 65536 f32
    float* ieff = iefc + BB * TT;                            // 65536 f32

    k_pack<<<1540, 256, 0, stream>>>(aW1, Whh, bih, bhh, aW1h, WhhH, bias);
    k_encproj<<<2048, 256, 0, stream>>>(ie, aW1, fcW, ffW, ep, iefc, ieff);
    k_main<<<BB / NB, NTHR, 0, stream>>>(ep, yh, aW1h, WhhH, bias, ab1, aW2,
                                         Wih, fcW, fcb, ffW, ffb, iefc, ieff, out);
}

// Round 14
// 4068.633 us; speedup vs baseline: 3.3113x; 3.3113x over previous
//
#include <hip/hip_runtime.h>

// DA-RNN decoder: B=512, T=128, E=256, D=256, OUT=1.
// R14 = R6 skeleton (one 1024-thread block/CU, NB=2, ep in LDS, lockstep,
// immediate-consume loads, <=50 live VGPRs per phase) with the LDS pipe
// (diagnosed as the real phase-A bottleneck: 96 b128 broadcast reads/thread)
// cut ~2x:
//  - gates: 2 rows x K-half per thread -> each h-read feeds 4 dots; partials
//    in s_gp[2][b][1024], summed in phase D.
//  - q fused in: thread's q-task K-range == its gates K-half, so qsel=0
//    threads reuse h0/h1 regs (no extra LDS). aW1 read once (768KB/step).
//  - iefc/ieff/yh/wih -> per-step global reads (L1-hot) to fit s_gp in LDS.
//  - pre-exp'd ep (scores are rcp-only); s_qp f-linear -> float4 qs reads.
// 3 barriers/step.

#define BB 512
#define TT 128
#define EE 256
#define DD 256
#define NB 2
#define NTHR 1024

typedef _Float16 h2 __attribute__((ext_vector_type(2)));
typedef _Float16 h8 __attribute__((ext_vector_type(8)));

#if defined(__has_builtin)
#if __has_builtin(__builtin_amdgcn_fdot2)
#define HAS_FDOT2 1
#endif
#endif

#ifdef HAS_FDOT2
#define FDOT2(a, b, c) __builtin_amdgcn_fdot2(__builtin_bit_cast(h2, (a)), __builtin_bit_cast(h2, (b)), (c), false)
#else
static __device__ __forceinline__ float FDOT2(unsigned int a, unsigned int b, float c) {
    h2 x = __builtin_bit_cast(h2, a), y = __builtin_bit_cast(h2, b);
    return c + (float)x[0] * (float)y[0] + (float)x[1] * (float)y[1];
}
#endif

static __device__ __forceinline__ float dot8u4(uint4 w, uint4 h, float acc) {
    acc = FDOT2(w.x, h.x, acc);
    acc = FDOT2(w.y, h.y, acc);
    acc = FDOT2(w.z, h.z, acc);
    acc = FDOT2(w.w, h.w, acc);
    return acc;
}
static __device__ __forceinline__ unsigned int pkh(float a, float b) {
    union { _Float16 h; unsigned short s; } ua, ub;
    ua.h = (_Float16)a; ub.h = (_Float16)b;
    return (unsigned int)ua.s | ((unsigned int)ub.s << 16);
}
__device__ __forceinline__ float ftanh(float x) {
    return 1.f - 2.f * __builtin_amdgcn_rcpf(__expf(2.f * x) + 1.f);
}
__device__ __forceinline__ float fsig(float x) {
    return __builtin_amdgcn_rcpf(1.f + __expf(-x));
}

// Pack weights to f16 in the exact load order of k_main.
// aW1h[(g*256+f)*8+j] = aW1[g*8+j][f]      (g<64, k=g*8+j < 512)
// WhhH[(i*1024+jj)*8+m] = Whh[jj][i*8+m]   (i<32)
__global__ __launch_bounds__(256) void k_pack(const float* __restrict__ aW1,
                                              const float* __restrict__ Whh,
                                              const float* __restrict__ bih,
                                              const float* __restrict__ bhh,
                                              _Float16* __restrict__ aW1h,
                                              _Float16* __restrict__ WhhH,
                                              float* __restrict__ bias) {
    int bid = blockIdx.x, tid = threadIdx.x;
    if (bid < 512) {
        int o = bid * 256 + tid;                 // < 131072
        int g = o >> 11, f = (o >> 3) & 255, j = o & 7;
        aW1h[o] = (_Float16)aW1[(g * 8 + j) * EE + f];
    } else if (bid < 1536) {
        int o = (bid - 512) * 256 + tid;         // < 262144
        int i = o >> 13, jj = (o >> 3) & 1023, m = o & 7;
        WhhH[o] = (_Float16)Whh[jj * DD + i * 8 + m];
    } else {
        int j = (bid - 1536) * 256 + tid;        // < 1024
        bias[j] = bih[j] + bhh[j];
    }
}

// pe[n][f] = f16( exp(2 * sum_e ie[n][e]*aW1[512+e][f]) )  (pre-exponentiated)
// epilogue: iefc[n] = dot(ie[n], fcW[0:256]); ieff[n] = dot(ie[n], ffW[256:512])
__global__ __launch_bounds__(256) void k_encproj(const float* __restrict__ ie,
                                                 const float* __restrict__ aW1,
                                                 const float* __restrict__ fcW,
                                                 const float* __restrict__ ffW,
                                                 _Float16* __restrict__ ep,
                                                 float* __restrict__ iefc,
                                                 float* __restrict__ ieff) {
    __shared__ float a[32][EE];
    int row0 = blockIdx.x * 32;
    int tid = threadIdx.x;
    for (int r = 0; r < 32; ++r)
        a[r][tid] = ie[(size_t)(row0 + r) * EE + tid];
    __syncthreads();
    float acc[32];
    #pragma unroll
    for (int r = 0; r < 32; ++r) acc[r] = 0.f;
    const float* wenc = aW1 + 512 * EE;
    for (int e = 0; e < EE; e += 4) {
        float w0 = wenc[(e + 0) * EE + tid];
        float w1 = wenc[(e + 1) * EE + tid];
        float w2 = wenc[(e + 2) * EE + tid];
        float w3 = wenc[(e + 3) * EE + tid];
        #pragma unroll
        for (int r = 0; r < 32; ++r) {
            float4 av = *(const float4*)&a[r][e];
            acc[r] += av.x * w0 + av.y * w1 + av.z * w2 + av.w * w3;
        }
    }
    for (int r = 0; r < 32; ++r)
        ep[(size_t)(row0 + r) * EE + tid] =
            (_Float16)fminf(__expf(2.f * acc[r]), 60000.f);

    int wave = tid >> 6, lane = tid & 63;
    float4 f1 = *(const float4*)&fcW[lane * 4];
    float4 f2 = *(const float4*)&ffW[EE + lane * 4];
    #pragma unroll
    for (int rr = 0; rr < 8; ++rr) {
        int r = wave * 8 + rr;
        float4 v = *(const float4*)&a[r][lane * 4];
        float p1 = v.x * f1.x + v.y * f1.y + v.z * f1.z + v.w * f1.w;
        float p2 = v.x * f2.x + v.y * f2.y + v.z * f2.z + v.w * f2.w;
        #pragma unroll
        for (int off = 1; off <= 32; off <<= 1) {
            p1 += __shfl_xor(p1, off);
            p2 += __shfl_xor(p2, off);
        }
        if (lane == 0) {
            iefc[row0 + r] = p1;
            ieff[row0 + r] = p2;
        }
    }
}

__global__ __launch_bounds__(NTHR) void k_main(
    const _Float16* __restrict__ ep, const float* __restrict__ yh,
    const _Float16* __restrict__ aW1h, const _Float16* __restrict__ WhhH,
    const float* __restrict__ bias_, const float* __restrict__ ab1,
    const float* __restrict__ aW2, const float* __restrict__ Wih,
    const float* __restrict__ fcW, const float* __restrict__ fcb,
    const float* __restrict__ ffW, const float* __restrict__ ffb,
    const float* __restrict__ iefc, const float* __restrict__ ieff,
    float* __restrict__ out) {
    __shared__ _Float16 s_ep[NB * TT * EE];      // 128 KB: pre-exp'd pe slice
    __shared__ unsigned int s_hc16[NB][2][128];  // [b][0=h,1=c], f16 pairs
    __shared__ float s_qp[4][NB][EE];            // [kq][b][f] (f-linear!) 8 KB
    __shared__ float s_gp[2][NB][4 * DD];        // [kh][b][row] partials 16 KB
    __shared__ float s_sc[NB * TT];              // 1 KB

    const int tid = threadIdx.x;
    const int wave = tid >> 6, lane = tid & 63;
    const int b0 = blockIdx.x * NB;

    // one-time staging of pe slice
    {
        const uint4* src = (const uint4*)(ep + (size_t)b0 * TT * EE);
        uint4* dst = (uint4*)s_ep;
        #pragma unroll
        for (int i = 0; i < (NB * TT * EE) / 8 / NTHR; ++i)
            dst[tid + i * NTHR] = src[tid + i * NTHR];
    }
    for (int i = tid; i < NB * 2 * 128; i += NTHR) (&s_hc16[0][0][0])[i] = 0u;

    // ----- fused phase-A mapping -----
    const int kh = tid >> 9;                     // gates K-half (0,1)
    const int x  = tid & 511;                    // gate row pair (x, x+512)
    const int f  = tid & 255;                    // q column
    const int qsel = (tid >> 8) & 1;             // 0: q operand = h (shared!)
    const int kq = qsel ? (2 + kh) : kh;         // q K-quarter
    const int gc0 = kh * 16;                     // chunk base (16B chunks)
    const uint4* wP1 = (const uint4*)WhhH + x;
    const uint4* wP2 = (const uint4*)WhhH + x + 512;
    const uint4* qWb = (const uint4*)aW1h + (size_t)(kq * 16) * 256 + f;
    const float bias1 = kh ? 0.f : bias_[x];
    const float bias2 = kh ? 0.f : bias_[x + 512];
    const float qinit = (kq == 0) ? ab1[f] : 0.f;

    // ----- scores mapping -----
    const int l5 = lane & 31;
    const int rsub = wave * 2 + (lane >> 5);     // [0,32)
    const int e0 = l5 * 8;
    float tw2[8]; float sw2 = 0.f;
    #pragma unroll
    for (int j = 0; j < 8; ++j) { float w = aW2[e0 + j]; tw2[j] = 2.f * w; sw2 += w; }

    // ----- softmax/update mapping -----
    const int bsm = (wave >> 2) & 1;             // waves 0-3:b0, 4-7:b1
    const int dd = tid & 255;
    const float fcw256 = fcW[256], fcb0 = fcb[0], ffb0 = ffb[0];
    const float* iefcb = iefc + (size_t)(b0 + bsm) * TT;
    const float* ieffb = ieff + (size_t)(b0 + bsm) * TT;
    const float* yhb   = yh + (size_t)(b0 + bsm) * TT;
    float c_reg = 0.f;                           // fp32 cell state (tid<512)
    float ofs_reg = 0.f;

    __syncthreads();

    for (int t = 0; t < TT; ++t) {
        // ---------- A: fused gates(2 rows, K-half) + q(1 col, K-quarter) ----------
        float g10 = bias1, g11 = bias1, g20 = bias2, g21 = bias2;
        float qa0 = qinit, qa1 = qinit;
        if (qsel == 0) {                         // q operand == gates operand (h)
            #pragma unroll
            for (int i = 0; i < 16; ++i) {
                uint4 gw1 = wP1[(size_t)(gc0 + i) * 1024];
                uint4 gw2 = wP2[(size_t)(gc0 + i) * 1024];
                uint4 qw  = qWb[(size_t)i * 256];
                uint4 h0 = *(const uint4*)&s_hc16[0][0][(gc0 + i) * 4];
                uint4 h1 = *(const uint4*)&s_hc16[1][0][(gc0 + i) * 4];
                g10 = dot8u4(gw1, h0, g10); g11 = dot8u4(gw1, h1, g11);
                g20 = dot8u4(gw2, h0, g20); g21 = dot8u4(gw2, h1, g21);
                qa0 = dot8u4(qw, h0, qa0);  qa1 = dot8u4(qw, h1, qa1);
            }
        } else {                                 // q operand = c (extra 2 reads)
            #pragma unroll
            for (int i = 0; i < 16; ++i) {
                uint4 gw1 = wP1[(size_t)(gc0 + i) * 1024];
                uint4 gw2 = wP2[(size_t)(gc0 + i) * 1024];
                uint4 qw  = qWb[(size_t)i * 256];
                uint4 h0 = *(const uint4*)&s_hc16[0][0][(gc0 + i) * 4];
                uint4 h1 = *(const uint4*)&s_hc16[1][0][(gc0 + i) * 4];
                uint4 c0 = *(const uint4*)&s_hc16[0][1][(gc0 + i) * 4];
                uint4 c1 = *(const uint4*)&s_hc16[1][1][(gc0 + i) * 4];
                g10 = dot8u4(gw1, h0, g10); g11 = dot8u4(gw1, h1, g11);
                g20 = dot8u4(gw2, h0, g20); g21 = dot8u4(gw2, h1, g21);
                qa0 = dot8u4(qw, c0, qa0);  qa1 = dot8u4(qw, c1, qa1);
            }
        }
        s_qp[kq][0][f] = qa0;
        s_qp[kq][1][f] = qa1;
        s_gp[kh][0][x] = g10;
        s_gp[kh][1][x] = g11;
        s_gp[kh][0][x + 512] = g20;
        s_gp[kh][1][x + 512] = g21;
        __syncthreads();

        // ---------- B: scores s[b][t'] = sw2 - sum_j 2w2j/(pe*pq+1) ----------
        #pragma unroll
        for (int b = 0; b < NB; ++b) {
            float4 qa = *(const float4*)&s_qp[0][b][e0];
            float4 qb = *(const float4*)&s_qp[0][b][e0 + 4];
            float4 ra = *(const float4*)&s_qp[1][b][e0];
            float4 rb = *(const float4*)&s_qp[1][b][e0 + 4];
            float4 sa = *(const float4*)&s_qp[2][b][e0];
            float4 sb = *(const float4*)&s_qp[2][b][e0 + 4];
            float4 ta = *(const float4*)&s_qp[3][b][e0];
            float4 tb = *(const float4*)&s_qp[3][b][e0 + 4];
            float pq[8];
            pq[0] = __expf(2.f * (qa.x + ra.x + sa.x + ta.x));
            pq[1] = __expf(2.f * (qa.y + ra.y + sa.y + ta.y));
            pq[2] = __expf(2.f * (qa.z + ra.z + sa.z + ta.z));
            pq[3] = __expf(2.f * (qa.w + ra.w + sa.w + ta.w));
            pq[4] = __expf(2.f * (qb.x + rb.x + sb.x + tb.x));
            pq[5] = __expf(2.f * (qb.y + rb.y + sb.y + tb.y));
            pq[6] = __expf(2.f * (qb.z + rb.z + sb.z + tb.z));
            pq[7] = __expf(2.f * (qb.w + rb.w + sb.w + tb.w));
            const _Float16* eph = s_ep + b * TT * EE + e0;
            #pragma unroll
            for (int sw = 0; sw < 4; ++sw) {
                int tt2 = sw * 32 + rsub;
                h8 xv = *(const h8*)(eph + tt2 * EE);
                float s = sw2;
                #pragma unroll
                for (int j = 0; j < 8; ++j) {
                    float den = __fmaf_rn((float)xv[j], pq[j], 1.f);
                    s = __fmaf_rn(-tw2[j], __builtin_amdgcn_rcpf(den), s);
                }
                #pragma unroll
                for (int off = 1; off <= 16; off <<= 1) s += __shfl_xor(s, off);
                if (l5 == 0) s_sc[b * TT + tt2] = s;
            }
        }
        __syncthreads();

        // ---------- C+D: all-wave shfl softmax + y_tilde + LSTM update ----------
        {
            float v0 = s_sc[bsm * TT + lane], v1 = s_sc[bsm * TT + 64 + lane];
            float m = fmaxf(v0, v1);
            #pragma unroll
            for (int off = 1; off <= 32; off <<= 1) m = fmaxf(m, __shfl_xor(m, off));
            float x0 = __expf(v0 - m), x1 = __expf(v1 - m);
            float ss = x0 + x1;
            #pragma unroll
            for (int off = 1; off <= 32; off <<= 1) ss += __shfl_xor(ss, off);
            float inv = __builtin_amdgcn_rcpf(ss);
            float a0 = x0 * inv, a1 = x1 * inv;
            float p = a0 * iefcb[lane] + a1 * iefcb[64 + lane];
            #pragma unroll
            for (int off = 1; off <= 32; off <<= 1) p += __shfl_xor(p, off);
            float yt = p + yhb[t] * fcw256 + fcb0;
            if (t == TT - 1) {
                float pf = a0 * ieffb[lane] + a1 * ieffb[64 + lane];
                #pragma unroll
                for (int off = 1; off <= 32; off <<= 1) pf += __shfl_xor(pf, off);
                ofs_reg = pf;
            }
            if (tid < NB * DD) {
                float gi = s_gp[0][bsm][dd]           + s_gp[1][bsm][dd]
                         + yt * Wih[dd];
                float gf = s_gp[0][bsm][DD + dd]      + s_gp[1][bsm][DD + dd]
                         + yt * Wih[DD + dd];
                float gg = s_gp[0][bsm][2 * DD + dd]  + s_gp[1][bsm][2 * DD + dd]
                         + yt * Wih[2 * DD + dd];
                float go = s_gp[0][bsm][3 * DD + dd]  + s_gp[1][bsm][3 * DD + dd]
                         + yt * Wih[3 * DD + dd];
                float c2 = fsig(gf) * c_reg + fsig(gi) * ftanh(gg);
                c_reg = c2;
                float hn = fsig(go) * ftanh(c2);
                float hO = __shfl_xor(hn, 1);
                float cO = __shfl_xor(c2, 1);
                if (!(dd & 1)) {
                    s_hc16[bsm][0][dd >> 1] = pkh(hn, hO);
                    s_hc16[bsm][1][dd >> 1] = pkh(c2, cO);
                }
            }
        }
        __syncthreads();
    }

    // ---------- final: out[b] = h.ffW[:256] + (attn_last . ieff) + ffb ----------
    if (wave == 0 || wave == 4) {
        int b = wave >> 2;
        unsigned int p0 = s_hc16[b][0][lane * 2];
        unsigned int p1 = s_hc16[b][0][lane * 2 + 1];
        h2 ha = __builtin_bit_cast(h2, p0), hb = __builtin_bit_cast(h2, p1);
        float4 w = *(const float4*)&ffW[lane * 4];
        float p = (float)ha[0] * w.x + (float)ha[1] * w.y
                + (float)hb[0] * w.z + (float)hb[1] * w.w;
        #pragma unroll
        for (int off = 1; off <= 32; off <<= 1) p += __shfl_xor(p, off);
        if (lane == 0) out[b0 + b] = p + ofs_reg + ffb0;
    }
}

extern "C" void kernel_launch(void* const* d_in, const int* in_sizes, int n_in,
                              void* d_out, int out_size, void* d_ws, size_t ws_size,
                              hipStream_t stream) {
    const float* ie  = (const float*)d_in[0];   // [B,T,E]
    const float* yh  = (const float*)d_in[1];   // [B,T,1]
    const float* aW1 = (const float*)d_in[2];   // [768,256]
    const float* ab1 = (const float*)d_in[3];   // [256]
    const float* aW2 = (const float*)d_in[4];   // [256,1]
    // d_in[5] = ab2: additive constant inside softmax -> invariant, unused
    const float* Wih = (const float*)d_in[6];   // [1024,1]
    const float* Whh = (const float*)d_in[7];   // [1024,256]
    const float* bih = (const float*)d_in[8];   // [1024]
    const float* bhh = (const float*)d_in[9];   // [1024]
    const float* fcW = (const float*)d_in[10];  // [1,257]
    const float* fcb = (const float*)d_in[11];  // [1]
    const float* ffW = (const float*)d_in[12];  // [1,512]
    const float* ffb = (const float*)d_in[13];  // [1]
    float* out = (float*)d_out;

    // workspace layout
    _Float16* ep   = (_Float16*)d_ws;                        // 16,777,216 f16 = 32 MiB
    _Float16* aW1h = ep + (size_t)BB * TT * EE;              // 131072 f16
    _Float16* WhhH = aW1h + 512 * EE;                        // 262144 f16
    float* bias = (float*)(WhhH + 262144);                   // 1024 f32
    float* iefc = bias + 1024;                               // 65536 f32
    float* ieff = iefc + BB * TT;                            // 65536 f32

    k_pack<<<1540, 256, 0, stream>>>(aW1, Whh, bih, bhh, aW1h, WhhH, bias);
    k_encproj<<<2048, 256, 0, stream>>>(ie, aW1, fcW, ffW, ep, iefc, ieff);
    k_main<<<BB / NB, NTHR, 0, stream>>>(ep, yh, aW1h, WhhH, bias, ab1, aW2,
                                         Wih, fcW, fcb, ffW, ffb, iefc, ieff, out);
}